// Round 5
// baseline (701.186 us; speedup 1.0000x reference)
//
#include <hip/hip_runtime.h>
#include <hip/hip_bf16.h>

typedef __bf16 bf16;
typedef __bf16 bf16x4 __attribute__((ext_vector_type(4)));
typedef __bf16 bf16x8 __attribute__((ext_vector_type(8)));
typedef float  f32x4  __attribute__((ext_vector_type(4)));

#define F_IN  128
#define C_MID 64
#define BN_EPSF 1e-5f

// ws layout:
//  floats [0..63] sum rawG, [64..127] sum rawG^2, [128..191] sum rawX,
//         [192..255] sum rawX^2, [256],[257] sum s, sum s^2
//  floats [512...] s array (N floats)
//  byte offset 32 MB: gx scratch (256 MB bf16) [fallback d_out if ws small]
// gx layout (round-2 proven): group g: G block 2048 B at g*4096, X at +2048.
//  In-block: lane*32 B = [cb0 j0..3][cb1] | +16B: [cb2][cb3],
//  value = point (g*16 + quad*4 + j), channel (cb*16 + row16).

// PHASE 0: EXACT round-2 kernel (measured 295 us). Contiguous 1-KB wave
// loads, per-wave swizzled LDS transpose, MFMA vs LDS weights, raw stats,
// bf16 store of G,X in fragment layout.
__global__ __launch_bounds__(256, 4) void k_p0(
    const float* __restrict__ gate, const float* __restrict__ skip,
    const float* __restrict__ Wg,   const float* __restrict__ Wx,
    float* __restrict__ stats, bf16* __restrict__ gx, int ngroups)
{
  __shared__ bf16x8 wfrag[2][4][4][64];          // 32 KiB
  __shared__ __align__(16) bf16 atile[4][2048];  // 16 KiB
  __shared__ float  red[256];

  const int tid = threadIdx.x;

  for (int e = tid; e < 2048; e += 256) {
    const int mat = e >> 10, cb = (e >> 8) & 3, kc = (e >> 6) & 3, ln = e & 63;
    const int c  = cb*16 + (ln & 15);
    const int k0 = kc*32 + (ln >> 4)*8;
    const float* W = mat ? Wx : Wg;
    bf16x8 t;
#pragma unroll
    for (int j = 0; j < 8; ++j) t[j] = (bf16)W[(k0 + j)*C_MID + c];
    wfrag[mat][cb][kc][ln] = t;
  }
  red[tid] = 0.f;
  __syncthreads();

  const int lane = tid & 63, wid = tid >> 6;
  const int mat  = wid & 1;
  const int row16 = lane & 15, quad = lane >> 4;
  const float* src = mat ? skip : gate;

  const int stream0  = blockIdx.x*2 + (wid >> 1);
  const int nstreams = gridDim.x*2;

  bf16* at = atile[wid];
  float s1[4] = {0,0,0,0}, s2[4] = {0,0,0,0};

  for (int g = stream0; g < ngroups; g += nstreams) {
    const float* p = src + (size_t)g * 2048;
    f32x4 L[8];
#pragma unroll
    for (int i = 0; i < 8; ++i) L[i] = *(const f32x4*)(p + i*256 + lane*4);
#pragma unroll
    for (int i = 0; i < 8; ++i) {
      const int r = i*2 + (lane >> 5);
      const int cbyte = ((lane & 31)*8) ^ ((r & 7) << 4);
      bf16x4 t;
#pragma unroll
      for (int j = 0; j < 4; ++j) t[j] = (bf16)L[i][j];
      *(bf16x4*)((char*)at + r*256 + cbyte) = t;
    }
    bf16x8 af[4];
#pragma unroll
    for (int kc = 0; kc < 4; ++kc) {
      const int cbyte = (kc*64 + quad*16) ^ ((row16 & 7) << 4);
      af[kc] = *(const bf16x8*)((const char*)at + row16*256 + cbyte);
    }
    f32x4 acc[4];
#pragma unroll
    for (int cb = 0; cb < 4; ++cb) acc[cb] = f32x4{0.f,0.f,0.f,0.f};
#pragma unroll
    for (int cb = 0; cb < 4; ++cb)
#pragma unroll
      for (int kc = 0; kc < 4; ++kc)
        acc[cb] = __builtin_amdgcn_mfma_f32_16x16x32_bf16(af[kc], wfrag[mat][cb][kc][lane], acc[cb], 0, 0, 0);

    bf16x8 o0, o1;
#pragma unroll
    for (int cb = 0; cb < 4; ++cb) {
#pragma unroll
      for (int j = 0; j < 4; ++j) {
        const float v = acc[cb][j];
        s1[cb] += v; s2[cb] += v*v;
        if (cb < 2) o0[cb*4 + j] = (bf16)v; else o1[(cb-2)*4 + j] = (bf16)v;
      }
    }
    char* dst = (char*)gx + ((size_t)g*2 + mat)*2048 + lane*32;
    *(bf16x8*)dst        = o0;
    *(bf16x8*)(dst + 16) = o1;
  }

#pragma unroll
  for (int cb = 0; cb < 4; ++cb) {
    s1[cb] += __shfl_xor(s1[cb], 16, 64);  s1[cb] += __shfl_xor(s1[cb], 32, 64);
    s2[cb] += __shfl_xor(s2[cb], 16, 64);  s2[cb] += __shfl_xor(s2[cb], 32, 64);
  }
  if (lane < 16) {
#pragma unroll
    for (int cb = 0; cb < 4; ++cb) {
      const int c = cb*16 + lane;
      atomicAdd(&red[mat*128 + c],      s1[cb]);
      atomicAdd(&red[mat*128 + 64 + c], s2[cb]);
    }
  }
  __syncthreads();
  atomicAdd(&stats[tid], red[tid]);
}

// PHASE 1 (rewritten, shuffle-free): per-wave LDS transpose of the gx
// fragments into [point][channel] (XOR-swizzled rows), fold BN + relu in
// VALU, then s = relu(z) @ Wpsi via 2 MFMAs with w replicated across B
// columns -> s[p] is lane-local in D (row = point). No cross-lane ops.
__global__ __launch_bounds__(256, 4) void k_p1(
    const bf16* __restrict__ gx, const float* __restrict__ stats,
    const float* __restrict__ gamma_g, const float* __restrict__ beta_g,
    const float* __restrict__ gamma_x, const float* __restrict__ beta_x,
    const float* __restrict__ Wpsi,
    float* __restrict__ sArr, float* __restrict__ sstat,
    int ngroups, float inv_n)
{
  __shared__ float pAg[64], pAx[64], pK[64];
  __shared__ __align__(16) bf16 tg_[4][1024];   // per-wave G tile 16x64 (swizzled)
  __shared__ __align__(16) bf16 tx_[4][1024];   // per-wave X tile

  const int tid = threadIdx.x;
  if (tid < 64) {
    const float mG = stats[tid]*inv_n,       vG = stats[64 + tid]*inv_n  - mG*mG;
    const float mX = stats[128 + tid]*inv_n, vX = stats[192 + tid]*inv_n - mX*mX;
    const float Ag = gamma_g[tid] * rsqrtf(vG + BN_EPSF);
    const float Ax = gamma_x[tid] * rsqrtf(vX + BN_EPSF);
    pAg[tid] = Ag; pAx[tid] = Ax;
    pK[tid]  = beta_g[tid] - mG*Ag + beta_x[tid] - mX*Ax;
  }
  __syncthreads();

  const int lane = tid & 63, wid = tid >> 6;
  const int r16 = lane & 15, q = lane >> 4;
  bf16* tg = tg_[wid];
  bf16* tx = tx_[wid];

  // per-lane params for channels q*8+j (frag0) and 32+q*8+j (frag1)
  float Ag0[8], Ax0[8], K0[8], Ag1[8], Ax1[8], K1[8];
  bf16x8 wf0, wf1;
#pragma unroll
  for (int j = 0; j < 8; ++j) {
    const int c0 = q*8 + j, c1 = 32 + q*8 + j;
    Ag0[j] = pAg[c0]; Ax0[j] = pAx[c0]; K0[j] = pK[c0];
    Ag1[j] = pAg[c1]; Ax1[j] = pAx[c1]; K1[j] = pK[c1];
    wf0[j] = (bf16)Wpsi[c0]; wf1[j] = (bf16)Wpsi[c1];
  }

  float aS = 0.f, aS2 = 0.f;
  const int g0 = blockIdx.x*4 + wid, ng = gridDim.x*4;
  const int swr = (r16 & 7) << 4;   // read-side row swizzle

  for (int g = g0; g < ngroups; g += ng) {
    const char* base = (const char*)gx + (size_t)g*4096 + lane*32;
    const bf16x8 e0 = *(const bf16x8*)(base);
    const bf16x8 e1 = *(const bf16x8*)(base + 16);
    const bf16x8 f0 = *(const bf16x8*)(base + 2048);
    const bf16x8 f1 = *(const bf16x8*)(base + 2048 + 16);
    // scatter into [point][channel] tiles, byte ^= (p&7)<<4
#pragma unroll
    for (int cb = 0; cb < 4; ++cb) {
#pragma unroll
      for (int j = 0; j < 4; ++j) {
        const int p = q*4 + j;
        const int boff = p*128 + ((((cb*16 + r16)*2)) ^ ((p & 7) << 4));
        const bf16 vG = (cb < 2) ? e0[cb*4 + j] : e1[(cb-2)*4 + j];
        const bf16 vX = (cb < 2) ? f0[cb*4 + j] : f1[(cb-2)*4 + j];
        *(bf16*)((char*)tg + boff) = vG;
        *(bf16*)((char*)tx + boff) = vX;
      }
    }
    // read as A-fragments: lane = point r16, k-slice q*8+j
    const bf16x8 aG0 = *(const bf16x8*)((const char*)tg + r16*128 + ((q*16)      ^ swr));
    const bf16x8 aG1 = *(const bf16x8*)((const char*)tg + r16*128 + ((64 + q*16) ^ swr));
    const bf16x8 aX0 = *(const bf16x8*)((const char*)tx + r16*128 + ((q*16)      ^ swr));
    const bf16x8 aX1 = *(const bf16x8*)((const char*)tx + r16*128 + ((64 + q*16) ^ swr));
    // fold BN + relu -> bf16 A operands
    bf16x8 a0, a1;
#pragma unroll
    for (int j = 0; j < 8; ++j) {
      float z0 = fmaf((float)aG0[j], Ag0[j], fmaf((float)aX0[j], Ax0[j], K0[j]));
      float z1 = fmaf((float)aG1[j], Ag1[j], fmaf((float)aX1[j], Ax1[j], K1[j]));
      a0[j] = (bf16)fmaxf(z0, 0.f);
      a1[j] = (bf16)fmaxf(z1, 0.f);
    }
    f32x4 acc = f32x4{0.f,0.f,0.f,0.f};
    acc = __builtin_amdgcn_mfma_f32_16x16x32_bf16(a0, wf0, acc, 0, 0, 0);
    acc = __builtin_amdgcn_mfma_f32_16x16x32_bf16(a1, wf1, acc, 0, 0, 0);
    // D: row = q*4 + reg = point, col = r16 (replicated) -> s lane-local
    if (r16 == 0) {
      *(f32x4*)&sArr[g*16 + q*4] = acc;
#pragma unroll
      for (int j = 0; j < 4; ++j) { aS += acc[j]; aS2 += acc[j]*acc[j]; }
    }
  }
  aS  += __shfl_xor(aS, 16, 64);  aS  += __shfl_xor(aS, 32, 64);
  aS2 += __shfl_xor(aS2,16, 64);  aS2 += __shfl_xor(aS2,32, 64);
  if (lane == 0) { atomicAdd(&sstat[0], aS); atomicAdd(&sstat[1], aS2); }
}

// PHASE 2: out = skip * sigmoid(BN(s))  (bpsi cancels in BN)
__global__ void k_out(const float* __restrict__ skip,
                      const float* __restrict__ sArr,
                      const float* __restrict__ sstat,
                      const float* __restrict__ gamma_psi,
                      const float* __restrict__ beta_psi,
                      float* __restrict__ out, int N)
{
  const float inv_n = 1.0f / (float)N;
  const float m = sstat[0] * inv_n;
  const float v = sstat[1] * inv_n - m*m;
  const float A = gamma_psi[0] * rsqrtf(v + BN_EPSF);
  const float B = beta_psi[0] - m*A;
  const long total  = (long)N * (F_IN/4);
  const long stride = (long)gridDim.x * blockDim.x;
  for (long i = (long)blockIdx.x*blockDim.x + threadIdx.x; i < total; i += stride) {
    const int p = (int)(i >> 5);
    const float t = sArr[p]*A + B;
    const float psi = 1.0f / (1.0f + __expf(-t));
    f32x4 vv = ((const f32x4*)skip)[i];
    ((f32x4*)out)[i] = vv * psi;
  }
}

extern "C" void kernel_launch(void* const* d_in, const int* in_sizes, int n_in,
                              void* d_out, int out_size, void* d_ws, size_t ws_size,
                              hipStream_t stream)
{
  const float* gate      = (const float*)d_in[0];
  const float* skip      = (const float*)d_in[1];
  const float* Wg        = (const float*)d_in[2];
  const float* gamma_g   = (const float*)d_in[4];
  const float* beta_g    = (const float*)d_in[5];
  const float* Wx        = (const float*)d_in[6];
  const float* gamma_x   = (const float*)d_in[8];
  const float* beta_x    = (const float*)d_in[9];
  const float* Wpsi      = (const float*)d_in[10];
  const float* gamma_psi = (const float*)d_in[12];
  const float* beta_psi  = (const float*)d_in[13];

  float* ws   = (float*)d_ws;
  float* sArr = ws + 512;
  float* out  = (float*)d_out;

  const int N = in_sizes[0] / F_IN;
  const int ngroups = N / 16;

  const size_t gx_off   = 32u * 1024u * 1024u;
  const size_t gx_bytes = (size_t)ngroups * 4096u;
  bf16* gx = (ws_size >= gx_off + gx_bytes)
                 ? (bf16*)((char*)d_ws + gx_off)
                 : (bf16*)d_out;

  hipMemsetAsync(d_ws, 0, 512*sizeof(float), stream);

  k_p0<<<dim3(1024), dim3(256), 0, stream>>>(gate, skip, Wg, Wx, ws, gx, ngroups);
  k_p1<<<dim3(2048), dim3(256), 0, stream>>>(gx, ws, gamma_g, beta_g, gamma_x, beta_x,
                                             Wpsi, sArr, ws + 256, ngroups, 1.0f/(float)N);
  k_out<<<dim3(2048), dim3(256), 0, stream>>>(skip, sArr, ws + 256, gamma_psi, beta_psi, out, N);
}

// Round 6
// 696.596 us; speedup vs baseline: 1.0066x; 1.0066x over previous
//
#include <hip/hip_runtime.h>
#include <hip/hip_bf16.h>

typedef __bf16 bf16;
typedef __bf16 bf16x4 __attribute__((ext_vector_type(4)));
typedef __bf16 bf16x8 __attribute__((ext_vector_type(8)));
typedef float  f32x4  __attribute__((ext_vector_type(4)));

#define F_IN  128
#define C_MID 64
#define BN_EPSF 1e-5f

// ws layout:
//  floats [0..63] sum rawG, [64..127] sum rawG^2, [128..191] sum rawX,
//         [192..255] sum rawX^2, [256],[257] sum s, sum s^2
//  floats [512...] s array (N floats)
//  byte offset 32 MB: gx scratch (256 MB bf16) [fallback d_out if ws small]
//
// gx layout (k_p1-native, chunk-major per 64-point group h):
//  base(h) = h*16384; G at +0, X at +8192.
//  addr = base + mat*8192 + k*1024 + l*16   (k = channel chunk 0..7, l = point 0..63)
//  16 B unit = channels 8k..8k+7 (bf16) of point h*64+l.

// PHASE 0: round-2 core (contiguous 1-KB wave loads, per-wave swizzled LDS
// transpose, MFMA vs LDS weights, raw stats) + NEW: post-MFMA per-wave LDS
// transpose of D into [point][channel], stored chunk-major for k_p1.
__global__ __launch_bounds__(256, 4) void k_p0(
    const float* __restrict__ gate, const float* __restrict__ skip,
    const float* __restrict__ Wg,   const float* __restrict__ Wx,
    float* __restrict__ stats, bf16* __restrict__ gx, int ngroups)
{
  __shared__ bf16x8 wfrag[2][4][4][64];          // 32 KiB
  __shared__ __align__(16) bf16 atile[4][2048];  // 16 KiB (A tile, reused for D transpose)
  __shared__ float  red[256];

  const int tid = threadIdx.x;

  for (int e = tid; e < 2048; e += 256) {
    const int mt = e >> 10, cb = (e >> 8) & 3, kc = (e >> 6) & 3, ln = e & 63;
    const int c  = cb*16 + (ln & 15);
    const int k0 = kc*32 + (ln >> 4)*8;
    const float* W = mt ? Wx : Wg;
    bf16x8 t;
#pragma unroll
    for (int j = 0; j < 8; ++j) t[j] = (bf16)W[(k0 + j)*C_MID + c];
    wfrag[mt][cb][kc][ln] = t;
  }
  red[tid] = 0.f;
  __syncthreads();

  const int lane = tid & 63, wid = tid >> 6;
  const int mat  = wid & 1;
  const int row16 = lane & 15, quad = lane >> 4;
  const float* src = mat ? skip : gate;

  const int stream0  = blockIdx.x*2 + (wid >> 1);
  const int nstreams = gridDim.x*2;

  bf16* at = atile[wid];
  float s1[4] = {0,0,0,0}, s2[4] = {0,0,0,0};

  // D-readback decomposition (constant per thread)
  const int c2  = lane >> 4;          // chunk pair selector 0..3
  const int pt  = lane & 15;          // point within 16-group
  const int swz = (pt & 7) << 4;

  for (int g = stream0; g < ngroups; g += nstreams) {
    const float* p = src + (size_t)g * 2048;
    f32x4 L[8];
#pragma unroll
    for (int i = 0; i < 8; ++i) L[i] = *(const f32x4*)(p + i*256 + lane*4);
#pragma unroll
    for (int i = 0; i < 8; ++i) {
      const int r = i*2 + (lane >> 5);
      const int cbyte = ((lane & 31)*8) ^ ((r & 7) << 4);
      bf16x4 t;
#pragma unroll
      for (int j = 0; j < 4; ++j) t[j] = (bf16)L[i][j];
      *(bf16x4*)((char*)at + r*256 + cbyte) = t;
    }
    bf16x8 af[4];
#pragma unroll
    for (int kc = 0; kc < 4; ++kc) {
      const int cbyte = (kc*64 + quad*16) ^ ((row16 & 7) << 4);
      af[kc] = *(const bf16x8*)((const char*)at + row16*256 + cbyte);
    }
    f32x4 acc[4];
#pragma unroll
    for (int cb = 0; cb < 4; ++cb) acc[cb] = f32x4{0.f,0.f,0.f,0.f};
#pragma unroll
    for (int cb = 0; cb < 4; ++cb)
#pragma unroll
      for (int kc = 0; kc < 4; ++kc)
        acc[cb] = __builtin_amdgcn_mfma_f32_16x16x32_bf16(af[kc], wfrag[mat][cb][kc][lane], acc[cb], 0, 0, 0);

    // stats + transpose D into per-wave LDS tile [point(16)][channel(64)*2B], swizzled
#pragma unroll
    for (int cb = 0; cb < 4; ++cb) {
#pragma unroll
      for (int j = 0; j < 4; ++j) {
        const float v = acc[cb][j];
        s1[cb] += v; s2[cb] += v*v;
        const int pp = quad*4 + j;
        const int c  = cb*16 + row16;
        *(bf16*)((char*)at + pp*128 + ((c*2) ^ ((pp & 7) << 4))) = (bf16)v;
      }
    }
    // read back per-point chunks and store chunk-major to gx
    const bf16x8 v0 = *(const bf16x8*)((const char*)at + pt*128 + (( c2     *16) ^ swz));
    const bf16x8 v1 = *(const bf16x8*)((const char*)at + pt*128 + (((c2+4)*16) ^ swz));
    char* b = (char*)gx + (size_t)(g >> 2)*16384 + (size_t)mat*8192 + ((g & 3)*16 + pt)*16;
    *(bf16x8*)(b + (size_t)c2*1024)     = v0;
    *(bf16x8*)(b + (size_t)(c2+4)*1024) = v1;
  }

#pragma unroll
  for (int cb = 0; cb < 4; ++cb) {
    s1[cb] += __shfl_xor(s1[cb], 16, 64);  s1[cb] += __shfl_xor(s1[cb], 32, 64);
    s2[cb] += __shfl_xor(s2[cb], 16, 64);  s2[cb] += __shfl_xor(s2[cb], 32, 64);
  }
  if (lane < 16) {
#pragma unroll
    for (int cb = 0; cb < 4; ++cb) {
      const int c = cb*16 + lane;
      atomicAdd(&red[mat*128 + c],      s1[cb]);
      atomicAdd(&red[mat*128 + 64 + c], s2[cb]);
    }
  }
  __syncthreads();
  atomicAdd(&stats[tid], red[tid]);
}

// PHASE 1: pure streaming. Lane = point. 16 coalesced 1-KB wave loads per
// 64-point group; per-channel params via wave-uniform LDS broadcast reads;
// fold BN + relu + dot(w) fully in-lane; lane-linear s store. No shuffles,
// no scatter, no barriers in the loop.
__global__ __launch_bounds__(256) void k_p1(
    const bf16* __restrict__ gx, const float* __restrict__ stats,
    const float* __restrict__ gamma_g, const float* __restrict__ beta_g,
    const float* __restrict__ gamma_x, const float* __restrict__ beta_x,
    const float* __restrict__ Wpsi,
    float* __restrict__ sArr, float* __restrict__ sstat,
    int ngroups64, float inv_n)
{
  __shared__ float pp[8*32];   // [chunk k][Ag0..7 | Ax0..7 | K0..7 | W0..7]
  const int tid = threadIdx.x;
  if (tid < 64) {
    const float mG = stats[tid]*inv_n,       vG = stats[64 + tid]*inv_n  - mG*mG;
    const float mX = stats[128 + tid]*inv_n, vX = stats[192 + tid]*inv_n - mX*mX;
    const float Ag = gamma_g[tid] * rsqrtf(vG + BN_EPSF);
    const float Ax = gamma_x[tid] * rsqrtf(vX + BN_EPSF);
    const int k = tid >> 3, j = tid & 7;
    pp[k*32 + j]      = Ag;
    pp[k*32 + 8  + j] = Ax;
    pp[k*32 + 16 + j] = beta_g[tid] - mG*Ag + beta_x[tid] - mX*Ax;
    pp[k*32 + 24 + j] = Wpsi[tid];
  }
  __syncthreads();

  const int lane = tid & 63, wid = tid >> 6;
  const f32x4* ppv = (const f32x4*)pp;
  float aS = 0.f, aS2 = 0.f;

  const int h0 = blockIdx.x*4 + wid, nh = gridDim.x*4;
  for (int h = h0; h < ngroups64; h += nh) {
    const char* bG = (const char*)gx + (size_t)h*16384 + lane*16;
    bf16x8 Gv[8], Xv[8];
#pragma unroll
    for (int k = 0; k < 8; ++k) {
      Gv[k] = *(const bf16x8*)(bG + k*1024);
      Xv[k] = *(const bf16x8*)(bG + 8192 + k*1024);
    }
    float s = 0.f;
#pragma unroll
    for (int k = 0; k < 8; ++k) {
      const f32x4 AgL = ppv[k*8+0], AgH = ppv[k*8+1];
      const f32x4 AxL = ppv[k*8+2], AxH = ppv[k*8+3];
      const f32x4 KL  = ppv[k*8+4], KH  = ppv[k*8+5];
      const f32x4 WL  = ppv[k*8+6], WH  = ppv[k*8+7];
#pragma unroll
      for (int j = 0; j < 4; ++j) {
        const float z0 = fmaf((float)Gv[k][j],     AgL[j], fmaf((float)Xv[k][j],     AxL[j], KL[j]));
        const float z1 = fmaf((float)Gv[k][4 + j], AgH[j], fmaf((float)Xv[k][4 + j], AxH[j], KH[j]));
        s = fmaf(fmaxf(z0, 0.f), WL[j], s);
        s = fmaf(fmaxf(z1, 0.f), WH[j], s);
      }
    }
    sArr[h*64 + lane] = s;
    aS += s; aS2 += s*s;
  }
#pragma unroll
  for (int m = 1; m <= 32; m <<= 1) {
    aS += __shfl_xor(aS, m, 64);  aS2 += __shfl_xor(aS2, m, 64);
  }
  if (lane == 0) { atomicAdd(&sstat[0], aS); atomicAdd(&sstat[1], aS2); }
}

// PHASE 2: out = skip * sigmoid(BN(s))  (bpsi cancels in BN)
__global__ void k_out(const float* __restrict__ skip,
                      const float* __restrict__ sArr,
                      const float* __restrict__ sstat,
                      const float* __restrict__ gamma_psi,
                      const float* __restrict__ beta_psi,
                      float* __restrict__ out, int N)
{
  const float inv_n = 1.0f / (float)N;
  const float m = sstat[0] * inv_n;
  const float v = sstat[1] * inv_n - m*m;
  const float A = gamma_psi[0] * rsqrtf(v + BN_EPSF);
  const float B = beta_psi[0] - m*A;
  const long total  = (long)N * (F_IN/4);
  const long stride = (long)gridDim.x * blockDim.x;
  for (long i = (long)blockIdx.x*blockDim.x + threadIdx.x; i < total; i += stride) {
    const int p = (int)(i >> 5);
    const float t = sArr[p]*A + B;
    const float psi = 1.0f / (1.0f + __expf(-t));
    f32x4 vv = ((const f32x4*)skip)[i];
    ((f32x4*)out)[i] = vv * psi;
  }
}

extern "C" void kernel_launch(void* const* d_in, const int* in_sizes, int n_in,
                              void* d_out, int out_size, void* d_ws, size_t ws_size,
                              hipStream_t stream)
{
  const float* gate      = (const float*)d_in[0];
  const float* skip      = (const float*)d_in[1];
  const float* Wg        = (const float*)d_in[2];
  const float* gamma_g   = (const float*)d_in[4];
  const float* beta_g    = (const float*)d_in[5];
  const float* Wx        = (const float*)d_in[6];
  const float* gamma_x   = (const float*)d_in[8];
  const float* beta_x    = (const float*)d_in[9];
  const float* Wpsi      = (const float*)d_in[10];
  const float* gamma_psi = (const float*)d_in[12];
  const float* beta_psi  = (const float*)d_in[13];

  float* ws   = (float*)d_ws;
  float* sArr = ws + 512;
  float* out  = (float*)d_out;

  const int N = in_sizes[0] / F_IN;
  const int ngroups   = N / 16;   // 16-point groups (k_p0)
  const int ngroups64 = N / 64;   // 64-point groups (k_p1)

  const size_t gx_off   = 32u * 1024u * 1024u;
  const size_t gx_bytes = (size_t)ngroups * 4096u;
  bf16* gx = (ws_size >= gx_off + gx_bytes)
                 ? (bf16*)((char*)d_ws + gx_off)
                 : (bf16*)d_out;

  hipMemsetAsync(d_ws, 0, 512*sizeof(float), stream);

  k_p0<<<dim3(1024), dim3(256), 0, stream>>>(gate, skip, Wg, Wx, ws, gx, ngroups);
  k_p1<<<dim3(2048), dim3(256), 0, stream>>>(gx, ws, gamma_g, beta_g, gamma_x, beta_x,
                                             Wpsi, sArr, ws + 256, ngroups64, 1.0f/(float)N);
  k_out<<<dim3(2048), dim3(256), 0, stream>>>(skip, sArr, ws + 256, gamma_psi, beta_psi, out, N);
}